// Round 14
// baseline (242.571 us; speedup 1.0000x reference)
//
#include <hip/hip_runtime.h>
#include <stdint.h>

#define SIZE 65535

typedef __bf16 bf16x8 __attribute__((ext_vector_type(8)));
typedef float floatx4 __attribute__((ext_vector_type(4)));

// ws layout (bf16 elements), FRAGMENT-LINEAR: chunk = tile*64 + lane, 8 elems/chunk.
#define WS_ENCW 0        // [nt8][kt8][lane][8]        -> 32768
#define WS_WIH  32768    // [nt8][g3][kt4][lane][8]    -> 49152
#define WS_WHH  81920    // [nt8][g3][kt4][lane][8]    -> 49152
#define WS_VW   131072   // [nt4][kt4][lane][8]        -> 8192
#define WS_DECW 139264   // [kt6][lane][8] (rows>=10 zero) -> 3072
#define WS_TOTC 17792    // total chunks (x64x8 elems = 142336)

__device__ __forceinline__ unsigned short f2bf(float f) {
    union { float f; unsigned int u; } v; v.f = f;
    unsigned int u = v.u;
    return (unsigned short)((u + 0x7fffu + ((u >> 16) & 1u)) >> 16);
}
// native cast -> hardware cvt (RNE, same rounding as manual)
__device__ __forceinline__ unsigned short f2bfn(float f) {
    union { __bf16 h; unsigned short s; } u; u.h = (__bf16)f;
    return u.s;
}
__device__ __forceinline__ float bf2f(unsigned short b) {
    union { unsigned int u; float f; } v; v.u = ((unsigned int)b) << 16;
    return v.f;
}
__device__ __forceinline__ float sigmf(float x) {
    x = fminf(fmaxf(x, -30.f), 30.f);
    return 1.f / (1.f + __expf(-x));
}
__device__ __forceinline__ float tanhfast(float x) {
    x = fminf(fmaxf(x, -15.f), 15.f);
    float e = __expf(2.f * x);
    return (e - 1.f) / (e + 1.f);
}

__device__ __forceinline__ bf16x8 cvt8g(const float* p) {
    float4 a = *reinterpret_cast<const float4*>(p);
    float4 b = *reinterpret_cast<const float4*>(p + 4);
    bf16x8 r;
    r[0] = (__bf16)a.x; r[1] = (__bf16)a.y; r[2] = (__bf16)a.z; r[3] = (__bf16)a.w;
    r[4] = (__bf16)b.x; r[5] = (__bf16)b.y; r[6] = (__bf16)b.z; r[7] = (__bf16)b.w;
    return r;
}
__device__ __forceinline__ bf16x8 ld8(const unsigned short* p) {
    return *reinterpret_cast<const bf16x8*>(p);
}

// async global->LDS, 16B per lane, no VGPR destination.
__device__ __forceinline__ void glds16(const unsigned short* g, unsigned short* l) {
    __builtin_amdgcn_global_load_lds(
        (const __attribute__((address_space(1))) unsigned int*)g,
        (__attribute__((address_space(3))) unsigned int*)l, 16, 0, 0);
}

// stage nfrags contiguous 1KB fragments; 8 waves split the slots
__device__ __forceinline__ void stage_seq(unsigned short* dst, const unsigned short* src,
                                          int nfrags, int wave, int lane) {
    for (int s = wave; s < nfrags; s += 8)
        glds16(src + s * 512 + lane * 8, dst + s * 512);
}
// stage one GRU chunk ng: slots 0..3 = w_ih kt0..3, slots 4..7 = w_hh kt0..3.
// 8 waves -> 1 frag each: wave w<4 stages ih kt=w; w>=4 stages hh kt=w-4.
__device__ __forceinline__ void stage_gru(unsigned short* dst, const unsigned short* wsw,
                                          int ng, int wave, int lane) {
    const int kt = wave & 3;
    const unsigned short* src = ((wave < 4) ? (wsw + WS_WIH) : (wsw + WS_WHH))
                                + (size_t)(ng * 4 + kt) * 512 + lane * 8;
    glds16(src, dst + wave * 512);
}

// ---------- pre-kernel: f32 weights -> bf16 fragment-linear layout ----------
__global__ __launch_bounds__(256) void cvt_weights(
    const float* __restrict__ enc_w, const float* __restrict__ w_ih,
    const float* __restrict__ w_hh, const float* __restrict__ v_w,
    const float* __restrict__ dec_w, unsigned short* __restrict__ ws) {
    int c = blockIdx.x * 256 + threadIdx.x;
    if (c >= WS_TOTC) return;
    const int lane = c & 63;
    const int l = lane & 15;
    const int q = lane >> 4;
    const float* src; int row, col, stride; bool zero = false;
    if (c < 4096) {                      // enc_w [nt8][kt8]
        int lt = c >> 6; int nt = lt >> 3, kt = lt & 7;
        row = nt * 16 + l; col = kt * 32 + q * 8; src = enc_w; stride = 256;
    } else if (c < 10240) {              // w_ih [nt8][g3][kt4]
        int lt = (c - 4096) >> 6; int nt = lt / 12; int r2 = lt % 12;
        int g = r2 >> 2, kt = r2 & 3;
        row = g * 128 + nt * 16 + l; col = kt * 32 + q * 8; src = w_ih; stride = 128;
    } else if (c < 16384) {              // w_hh
        int lt = (c - 10240) >> 6; int nt = lt / 12; int r2 = lt % 12;
        int g = r2 >> 2, kt = r2 & 3;
        row = g * 128 + nt * 16 + l; col = kt * 32 + q * 8; src = w_hh; stride = 128;
    } else if (c < 17408) {              // v_w [nt4][kt4]
        int lt = (c - 16384) >> 6; int nt = lt >> 2, kt = lt & 3;
        row = nt * 16 + l; col = kt * 32 + q * 8; src = v_w; stride = 128;
    } else {                             // dec_w [kt6], zero-pad rows 10..15
        int kt = (c - 17408) >> 6;
        row = l; col = kt * 32 + q * 8; src = dec_w; stride = 192;
        zero = (l >= 10);
    }
    float4 a, b;
    if (zero) { a = make_float4(0.f,0.f,0.f,0.f); b = a; }
    else {
        const float* p = src + (size_t)row * stride + col;
        a = *reinterpret_cast<const float4*>(p);
        b = *reinterpret_cast<const float4*>(p + 4);
    }
    unsigned short* d = ws + (size_t)c * 8;
    d[0]=f2bf(a.x); d[1]=f2bf(a.y); d[2]=f2bf(a.z); d[3]=f2bf(a.w);
    d[4]=f2bf(b.x); d[5]=f2bf(b.y); d[6]=f2bf(b.z); d[7]=f2bf(b.w);
}

// ---------- main fused kernel: R10 cadence at 24 waves/CU ----------
// Wave-count series on staged structures: 4 waves/CU = 94us (R13), 8 = 74
// (R2/R9), 16 = 72 (R10) — falling into an unlocated per-CU saturation knee.
// This round: 512-thread blocks (8 waves x 16 rows = 128 rows/block, grid
// 512), LDS 50KB -> 3 blocks/CU = 24 waves/CU. Staging traffic/CU -25%.
// launch_bounds(512,6) caps VGPR at 85 >= R10's measured 60 (no R6 spill).
// Cadence, chunk schedule, per-wave compute = R10 verbatim.
__global__ __launch_bounds__(512, 6) void attn_critic_kernel(
    const float* __restrict__ obs,    // [SIZE,256] f32
    const float* __restrict__ hid,    // [SIZE,128] f32
    const float* __restrict__ enc_b,  // [128] f32
    const float* __restrict__ b_ih,   // [384] f32
    const float* __restrict__ b_hh,   // [384] f32
    const float* __restrict__ v_b,    // [64] f32
    const float* __restrict__ dec_b,  // [10] f32
    const unsigned short* __restrict__ wsw,  // bf16 fragment-linear weights
    float* __restrict__ out)          // [SIZE*10] ++ [SIZE*128] f32
{
    // weight ring: 2 x 8KB (8 fragment slots each)
    __shared__ __align__(16) unsigned short wbuf[2][4096];
    // per-wave pool: sA [16][136]; sV [16][72] + sO overlay after h_out stored
    __shared__ __align__(16) unsigned short pool[8][2176];

    const int tid  = threadIdx.x;
    const int wave = tid >> 6;
    const int lane = tid & 63;
    const int l15  = lane & 15;
    const int quad = lane >> 4;
    const int wrow0 = (blockIdx.x * 8 + wave) * 16;

    unsigned short (*sA)[136] = (unsigned short(*)[136])&pool[wave][0];  // [16][136]
    unsigned short (*sV)[72]  = (unsigned short(*)[72]) &pool[wave][0];  // [16][72] overlay
    float* sO = (float*)&pool[wave][1152];                               // [16][10] overlay

    int rA0 = wrow0 + l15; rA0 = (rA0 < SIZE) ? rA0 : (SIZE - 1);

    // ---- stage phase-1 chunk 0; latency hides under the prefetch ----
    stage_seq(wbuf[0], wsw + WS_ENCW, 8, wave, lane);

    // ---- prefetch obs + hid A-fragments ----
    bf16x8 aob[8], hf[4];
    {
        const float* o0 = obs + (size_t)rA0 * 256;
#pragma unroll
        for (int kt = 0; kt < 8; ++kt)
            aob[kt] = cvt8g(o0 + kt * 32 + quad * 8);
        const float* h0 = hid + (size_t)rA0 * 128;
#pragma unroll
        for (int kt = 0; kt < 4; ++kt)
            hf[kt] = cvt8g(h0 + kt * 32 + quad * 8);
    }
    __builtin_amdgcn_sched_barrier(0);
    __syncthreads();   // chunk 0 staged

    // ---- Phase 1: X = relu(OBS @ enc_w^T + enc_b), chunks 0..7 ----
#pragma unroll 1
    for (int nt = 0; nt < 8; ++nt) {
        const int cur = nt & 1;
        if (nt < 7) stage_seq(wbuf[cur ^ 1], wsw + WS_ENCW + (nt + 1) * 4096, 8, wave, lane);
        else        stage_gru(wbuf[cur ^ 1], wsw, 0, wave, lane);   // phase-2 chunk 0
        const float bias = enc_b[nt * 16 + l15];
        floatx4 a0 = floatx4{0.f,0.f,0.f,0.f};
#pragma unroll
        for (int kt = 0; kt < 8; ++kt) {
            bf16x8 b = ld8(&wbuf[cur][kt * 512 + lane * 8]);
            a0 = __builtin_amdgcn_mfma_f32_16x16x32_bf16(aob[kt], b, a0, 0, 0, 0);
        }
#pragma unroll
        for (int r = 0; r < 4; ++r)
            sA[quad * 4 + r][nt * 16 + l15] = f2bfn(fmaxf(a0[r] + bias, 0.f));
        __syncthreads();   // staged chunk ready; all reads of wbuf[cur] done
    }

    bf16x8 xf[4];
#pragma unroll
    for (int kt = 0; kt < 4; ++kt)
        xf[kt] = ld8(&sA[l15][kt * 32 + quad * 8]);

    // ---- Phase 2: GRU cell (h_out bf16 -> sA), chunks ng=0..23 ----
#pragma unroll 1
    for (int nt = 0; nt < 8; ++nt) {
        const int nr = nt * 16 + l15;
        float hp[4];
#pragma unroll
        for (int r = 0; r < 4; ++r) {
            const int grow = wrow0 + quad * 4 + r;
            const int rowc = (grow < SIZE) ? grow : (SIZE - 1);
            hp[r] = hid[(size_t)rowc * 128 + nr];
        }
        const float bir_ = b_ih[nr], biz_ = b_ih[nr + 128], bin_ = b_ih[nr + 256];
        const float bhr_ = b_hh[nr], bhz_ = b_hh[nr + 128], bhn_ = b_hh[nr + 256];
        floatx4 gi[3], gh[3];
#pragma unroll
        for (int g = 0; g < 3; ++g) {
            gi[g] = floatx4{0.f,0.f,0.f,0.f};
            gh[g] = gi[g];
        }
#pragma unroll
        for (int g = 0; g < 3; ++g) {
            const int cur = (nt + g) & 1;
            const int ng = nt * 3 + g + 1;
            if (ng < 24) stage_gru(wbuf[cur ^ 1], wsw, ng, wave, lane);
            else         stage_seq(wbuf[cur ^ 1], wsw + WS_VW, 4, wave, lane); // phase-3 chunk 0
#pragma unroll
            for (int kt = 0; kt < 4; ++kt) {
                bf16x8 bi = ld8(&wbuf[cur][kt * 512 + lane * 8]);
                bf16x8 bh = ld8(&wbuf[cur][(4 + kt) * 512 + lane * 8]);
                gi[g] = __builtin_amdgcn_mfma_f32_16x16x32_bf16(xf[kt], bi, gi[g], 0, 0, 0);
                gh[g] = __builtin_amdgcn_mfma_f32_16x16x32_bf16(hf[kt], bh, gh[g], 0, 0, 0);
            }
            __syncthreads();
        }
#pragma unroll
        for (int r = 0; r < 4; ++r) {
            float rg = sigmf(gi[0][r] + bir_ + gh[0][r] + bhr_);
            float zg = sigmf(gi[1][r] + biz_ + gh[1][r] + bhz_);
            float ng2 = tanhfast(gi[2][r] + bin_ + rg * (gh[2][r] + bhn_));
            float ho = ng2 + zg * (hp[r] - ng2);
            sA[quad * 4 + r][nr] = f2bfn(ho);
        }
    }

    // ---- capture h_out fragments, store h_out (sA dies; sV/sO overlay) ----
    bf16x8 af[4];
#pragma unroll
    for (int kt = 0; kt < 4; ++kt)
        af[kt] = ld8(&sA[l15][kt * 32 + quad * 8]);
    {
        float* out_h = out + (size_t)SIZE * 10;
#pragma unroll 1
        for (int it = 0; it < 8; ++it) {
            int idx = it * 256 + lane * 4;   // over [16][128]
            int rr = idx >> 7, cc = idx & 127;
            int grow = wrow0 + rr;
            if (grow < SIZE) {
                float2 p0 = make_float2(bf2f(sA[rr][cc]),     bf2f(sA[rr][cc + 1]));
                float2 p1 = make_float2(bf2f(sA[rr][cc + 2]), bf2f(sA[rr][cc + 3]));
                float* dst = out_h + (size_t)grow * 128 + cc;
                *reinterpret_cast<float2*>(dst)     = p0;
                *reinterpret_cast<float2*>(dst + 2) = p1;
            }
        }
    }

    // ---- Phase 3: V = relu(H_OUT @ v_w^T + v_b) -> sV (overlay), chunks 0..3 ----
#pragma unroll 1
    for (int nt = 0; nt < 4; ++nt) {
        const int cur = nt & 1;
        if (nt < 3) stage_seq(wbuf[cur ^ 1], wsw + WS_VW + (nt + 1) * 2048, 4, wave, lane);
        else        stage_seq(wbuf[cur ^ 1], wsw + WS_DECW, 6, wave, lane);  // phase-4 chunk
        const float bias = v_b[nt * 16 + l15];
        floatx4 a0 = floatx4{0.f,0.f,0.f,0.f};
#pragma unroll
        for (int kt = 0; kt < 4; ++kt) {
            bf16x8 b = ld8(&wbuf[cur][kt * 512 + lane * 8]);
            a0 = __builtin_amdgcn_mfma_f32_16x16x32_bf16(af[kt], b, a0, 0, 0, 0);
        }
#pragma unroll
        for (int r = 0; r < 4; ++r)
            sV[quad * 4 + r][nt * 16 + l15] = f2bfn(fmaxf(a0[r] + bias, 0.f));
        __syncthreads();
    }

    // ---- Phase 4: OUT = [H_OUT|V] @ dec_w^T + dec_b (weights in wbuf[0]) ----
    {
        floatx4 d0 = floatx4{0.f,0.f,0.f,0.f};
#pragma unroll
        for (int kt = 0; kt < 6; ++kt) {
            bf16x8 b = ld8(&wbuf[0][kt * 512 + lane * 8]);
            bf16x8 a0 = (kt < 4) ? af[kt] : ld8(&sV[l15][(kt - 4) * 32 + quad * 8]);
            d0 = __builtin_amdgcn_mfma_f32_16x16x32_bf16(a0, b, d0, 0, 0, 0);
        }
        if (l15 < 10) {
            const float bias = dec_b[l15];
#pragma unroll
            for (int r = 0; r < 4; ++r)
                sO[(quad * 4 + r) * 10 + l15] = d0[r] + bias;
        }
        // coalesced store: 160 consecutive f32 per wave
#pragma unroll
        for (int j = 0; j < 3; ++j) {
            int idx = j * 64 + lane;          // 0..191, use 0..159
            if (idx < 160) {
                int row = idx / 10, col = idx % 10;
                int grow = wrow0 + row;
                if (grow < SIZE)
                    out[(size_t)grow * 10 + col] = sO[row * 10 + col];
            }
        }
    }
}

extern "C" void kernel_launch(void* const* d_in, const int* in_sizes, int n_in,
                              void* d_out, int out_size, void* d_ws, size_t ws_size,
                              hipStream_t stream) {
    const float* obs   = (const float*)d_in[0];
    const float* hid   = (const float*)d_in[1];
    const float* enc_w = (const float*)d_in[2];
    const float* enc_b = (const float*)d_in[3];
    const float* w_ih  = (const float*)d_in[4];
    const float* w_hh  = (const float*)d_in[5];
    const float* b_ih  = (const float*)d_in[6];
    const float* b_hh  = (const float*)d_in[7];
    // d_in[8..19]: dead code (bi-GRU / hard attention / q,k) — unused.
    const float* v_w   = (const float*)d_in[20];
    const float* v_b   = (const float*)d_in[21];
    const float* dec_w = (const float*)d_in[22];
    const float* dec_b = (const float*)d_in[23];
    unsigned short* wsw = (unsigned short*)d_ws;
    float* out = (float*)d_out;

    hipLaunchKernelGGL(cvt_weights, dim3((WS_TOTC + 255) / 256), dim3(256), 0, stream,
                       enc_w, w_ih, w_hh, v_w, dec_w, wsw);
    // 512 blocks x 8 waves x 16 rows = 65536 >= 65535; 3 blocks/CU = 24 waves/CU
    hipLaunchKernelGGL(attn_critic_kernel, dim3(512), dim3(512), 0, stream,
                       obs, hid, enc_b, b_ih, b_hh, v_b, dec_b, wsw, out);
}

// Round 15
// 206.502 us; speedup vs baseline: 1.1747x; 1.1747x over previous
//
#include <hip/hip_runtime.h>
#include <stdint.h>

#define SIZE 65535

typedef __bf16 bf16x8 __attribute__((ext_vector_type(8)));
typedef float floatx4 __attribute__((ext_vector_type(4)));

// ws layout (bf16 elements), FRAGMENT-LINEAR: chunk = tile*64 + lane, 8 elems/chunk.
#define WS_ENCW 0        // [nt8][kt8][lane][8]        -> 32768
#define WS_WIH  32768    // [nt8][g3][kt4][lane][8]    -> 49152
#define WS_WHH  81920    // [nt8][g3][kt4][lane][8]    -> 49152
#define WS_VW   131072   // [nt4][kt4][lane][8]        -> 8192
#define WS_DECW 139264   // [kt6][lane][8] (rows>=10 zero) -> 3072
#define WS_TOTC 17792    // total chunks (x64x8 elems = 142336)

__device__ __forceinline__ unsigned short f2bf(float f) {
    union { float f; unsigned int u; } v; v.f = f;
    unsigned int u = v.u;
    return (unsigned short)((u + 0x7fffu + ((u >> 16) & 1u)) >> 16);
}
// native cast -> hardware cvt (RNE, same rounding as manual)
__device__ __forceinline__ unsigned short f2bfn(float f) {
    union { __bf16 h; unsigned short s; } u; u.h = (__bf16)f;
    return u.s;
}
__device__ __forceinline__ float bf2f(unsigned short b) {
    union { unsigned int u; float f; } v; v.u = ((unsigned int)b) << 16;
    return v.f;
}
__device__ __forceinline__ float sigmf(float x) {
    x = fminf(fmaxf(x, -30.f), 30.f);
    return 1.f / (1.f + __expf(-x));
}
__device__ __forceinline__ float tanhfast(float x) {
    x = fminf(fmaxf(x, -15.f), 15.f);
    float e = __expf(2.f * x);
    return (e - 1.f) / (e + 1.f);
}

__device__ __forceinline__ bf16x8 cvt8g(const float* p) {
    float4 a = *reinterpret_cast<const float4*>(p);
    float4 b = *reinterpret_cast<const float4*>(p + 4);
    bf16x8 r;
    r[0] = (__bf16)a.x; r[1] = (__bf16)a.y; r[2] = (__bf16)a.z; r[3] = (__bf16)a.w;
    r[4] = (__bf16)b.x; r[5] = (__bf16)b.y; r[6] = (__bf16)b.z; r[7] = (__bf16)b.w;
    return r;
}
__device__ __forceinline__ bf16x8 ld8(const unsigned short* p) {
    return *reinterpret_cast<const bf16x8*>(p);
}

// async global->LDS, 16B per lane, no VGPR destination.
__device__ __forceinline__ void glds16(const unsigned short* g, unsigned short* l) {
    __builtin_amdgcn_global_load_lds(
        (const __attribute__((address_space(1))) unsigned int*)g,
        (__attribute__((address_space(3))) unsigned int*)l, 16, 0, 0);
}

// stage nfrags contiguous 1KB fragments; 8 waves split the slots
__device__ __forceinline__ void stage_seq(unsigned short* dst, const unsigned short* src,
                                          int nfrags, int wave, int lane) {
    for (int s = wave; s < nfrags; s += 8)
        glds16(src + s * 512 + lane * 8, dst + s * 512);
}
// stage one GRU chunk ng: slots 0..3 = w_ih kt0..3, slots 4..7 = w_hh kt0..3.
// 8 waves -> 1 frag each: wave w<4 stages ih kt=w; w>=4 stages hh kt=w-4.
__device__ __forceinline__ void stage_gru(unsigned short* dst, const unsigned short* wsw,
                                          int ng, int wave, int lane) {
    const int kt = wave & 3;
    const unsigned short* src = ((wave < 4) ? (wsw + WS_WIH) : (wsw + WS_WHH))
                                + (size_t)(ng * 4 + kt) * 512 + lane * 8;
    glds16(src, dst + wave * 512);
}

// ---------- pre-kernel: f32 weights -> bf16 fragment-linear layout ----------
__global__ __launch_bounds__(256) void cvt_weights(
    const float* __restrict__ enc_w, const float* __restrict__ w_ih,
    const float* __restrict__ w_hh, const float* __restrict__ v_w,
    const float* __restrict__ dec_w, unsigned short* __restrict__ ws) {
    int c = blockIdx.x * 256 + threadIdx.x;
    if (c >= WS_TOTC) return;
    const int lane = c & 63;
    const int l = lane & 15;
    const int q = lane >> 4;
    const float* src; int row, col, stride; bool zero = false;
    if (c < 4096) {                      // enc_w [nt8][kt8]
        int lt = c >> 6; int nt = lt >> 3, kt = lt & 7;
        row = nt * 16 + l; col = kt * 32 + q * 8; src = enc_w; stride = 256;
    } else if (c < 10240) {              // w_ih [nt8][g3][kt4]
        int lt = (c - 4096) >> 6; int nt = lt / 12; int r2 = lt % 12;
        int g = r2 >> 2, kt = r2 & 3;
        row = g * 128 + nt * 16 + l; col = kt * 32 + q * 8; src = w_ih; stride = 128;
    } else if (c < 16384) {              // w_hh
        int lt = (c - 10240) >> 6; int nt = lt / 12; int r2 = lt % 12;
        int g = r2 >> 2, kt = r2 & 3;
        row = g * 128 + nt * 16 + l; col = kt * 32 + q * 8; src = w_hh; stride = 128;
    } else if (c < 17408) {              // v_w [nt4][kt4]
        int lt = (c - 16384) >> 6; int nt = lt >> 2, kt = lt & 3;
        row = nt * 16 + l; col = kt * 32 + q * 8; src = v_w; stride = 128;
    } else {                             // dec_w [kt6], zero-pad rows 10..15
        int kt = (c - 17408) >> 6;
        row = l; col = kt * 32 + q * 8; src = dec_w; stride = 192;
        zero = (l >= 10);
    }
    float4 a, b;
    if (zero) { a = make_float4(0.f,0.f,0.f,0.f); b = a; }
    else {
        const float* p = src + (size_t)row * stride + col;
        a = *reinterpret_cast<const float4*>(p);
        b = *reinterpret_cast<const float4*>(p + 4);
    }
    unsigned short* d = ws + (size_t)c * 8;
    d[0]=f2bf(a.x); d[1]=f2bf(a.y); d[2]=f2bf(a.z); d[3]=f2bf(a.w);
    d[4]=f2bf(b.x); d[5]=f2bf(b.y); d[6]=f2bf(b.z); d[7]=f2bf(b.w);
}

// ---------- main fused kernel: R14 structure, UNPOISONED register budget ----------
// R14's (512,6) second-arg crushed VGPR to 40 (natural demand ~60, R10) ->
// spill storm (FETCH 114MB / WRITE 93MB). This round: plain
// __launch_bounds__(512) -> compiler allocates natural ~60-85 VGPR, LDS 50KB
// limits occupancy at 3 blocks/CU = 24 waves/CU (clean top point of the
// wave-series: 4w=94us, 8w=74, 16w=72, 24w=?). Everything else R14 verbatim
// (which passed correctness). If VGPR lands >85 the fallback is 16 waves/CU
// = R10-equivalent; bounded downside.
__global__ __launch_bounds__(512) void attn_critic_kernel(
    const float* __restrict__ obs,    // [SIZE,256] f32
    const float* __restrict__ hid,    // [SIZE,128] f32
    const float* __restrict__ enc_b,  // [128] f32
    const float* __restrict__ b_ih,   // [384] f32
    const float* __restrict__ b_hh,   // [384] f32
    const float* __restrict__ v_b,    // [64] f32
    const float* __restrict__ dec_b,  // [10] f32
    const unsigned short* __restrict__ wsw,  // bf16 fragment-linear weights
    float* __restrict__ out)          // [SIZE*10] ++ [SIZE*128] f32
{
    // weight ring: 2 x 8KB (8 fragment slots each)
    __shared__ __align__(16) unsigned short wbuf[2][4096];
    // per-wave pool: sA [16][136]; sV [16][72] + sO overlay after h_out stored
    __shared__ __align__(16) unsigned short pool[8][2176];

    const int tid  = threadIdx.x;
    const int wave = tid >> 6;
    const int lane = tid & 63;
    const int l15  = lane & 15;
    const int quad = lane >> 4;
    const int wrow0 = (blockIdx.x * 8 + wave) * 16;

    unsigned short (*sA)[136] = (unsigned short(*)[136])&pool[wave][0];  // [16][136]
    unsigned short (*sV)[72]  = (unsigned short(*)[72]) &pool[wave][0];  // [16][72] overlay
    float* sO = (float*)&pool[wave][1152];                               // [16][10] overlay

    int rA0 = wrow0 + l15; rA0 = (rA0 < SIZE) ? rA0 : (SIZE - 1);

    // ---- stage phase-1 chunk 0; latency hides under the prefetch ----
    stage_seq(wbuf[0], wsw + WS_ENCW, 8, wave, lane);

    // ---- prefetch obs + hid A-fragments ----
    bf16x8 aob[8], hf[4];
    {
        const float* o0 = obs + (size_t)rA0 * 256;
#pragma unroll
        for (int kt = 0; kt < 8; ++kt)
            aob[kt] = cvt8g(o0 + kt * 32 + quad * 8);
        const float* h0 = hid + (size_t)rA0 * 128;
#pragma unroll
        for (int kt = 0; kt < 4; ++kt)
            hf[kt] = cvt8g(h0 + kt * 32 + quad * 8);
    }
    __builtin_amdgcn_sched_barrier(0);
    __syncthreads();   // chunk 0 staged

    // ---- Phase 1: X = relu(OBS @ enc_w^T + enc_b), chunks 0..7 ----
#pragma unroll 1
    for (int nt = 0; nt < 8; ++nt) {
        const int cur = nt & 1;
        if (nt < 7) stage_seq(wbuf[cur ^ 1], wsw + WS_ENCW + (nt + 1) * 4096, 8, wave, lane);
        else        stage_gru(wbuf[cur ^ 1], wsw, 0, wave, lane);   // phase-2 chunk 0
        const float bias = enc_b[nt * 16 + l15];
        floatx4 a0 = floatx4{0.f,0.f,0.f,0.f};
#pragma unroll
        for (int kt = 0; kt < 8; ++kt) {
            bf16x8 b = ld8(&wbuf[cur][kt * 512 + lane * 8]);
            a0 = __builtin_amdgcn_mfma_f32_16x16x32_bf16(aob[kt], b, a0, 0, 0, 0);
        }
#pragma unroll
        for (int r = 0; r < 4; ++r)
            sA[quad * 4 + r][nt * 16 + l15] = f2bfn(fmaxf(a0[r] + bias, 0.f));
        __syncthreads();   // staged chunk ready; all reads of wbuf[cur] done
    }

    bf16x8 xf[4];
#pragma unroll
    for (int kt = 0; kt < 4; ++kt)
        xf[kt] = ld8(&sA[l15][kt * 32 + quad * 8]);

    // ---- Phase 2: GRU cell (h_out bf16 -> sA), chunks ng=0..23 ----
#pragma unroll 1
    for (int nt = 0; nt < 8; ++nt) {
        const int nr = nt * 16 + l15;
        float hp[4];
#pragma unroll
        for (int r = 0; r < 4; ++r) {
            const int grow = wrow0 + quad * 4 + r;
            const int rowc = (grow < SIZE) ? grow : (SIZE - 1);
            hp[r] = hid[(size_t)rowc * 128 + nr];
        }
        const float bir_ = b_ih[nr], biz_ = b_ih[nr + 128], bin_ = b_ih[nr + 256];
        const float bhr_ = b_hh[nr], bhz_ = b_hh[nr + 128], bhn_ = b_hh[nr + 256];
        floatx4 gi[3], gh[3];
#pragma unroll
        for (int g = 0; g < 3; ++g) {
            gi[g] = floatx4{0.f,0.f,0.f,0.f};
            gh[g] = gi[g];
        }
#pragma unroll
        for (int g = 0; g < 3; ++g) {
            const int cur = (nt + g) & 1;
            const int ng = nt * 3 + g + 1;
            if (ng < 24) stage_gru(wbuf[cur ^ 1], wsw, ng, wave, lane);
            else         stage_seq(wbuf[cur ^ 1], wsw + WS_VW, 4, wave, lane); // phase-3 chunk 0
#pragma unroll
            for (int kt = 0; kt < 4; ++kt) {
                bf16x8 bi = ld8(&wbuf[cur][kt * 512 + lane * 8]);
                bf16x8 bh = ld8(&wbuf[cur][(4 + kt) * 512 + lane * 8]);
                gi[g] = __builtin_amdgcn_mfma_f32_16x16x32_bf16(xf[kt], bi, gi[g], 0, 0, 0);
                gh[g] = __builtin_amdgcn_mfma_f32_16x16x32_bf16(hf[kt], bh, gh[g], 0, 0, 0);
            }
            __syncthreads();
        }
#pragma unroll
        for (int r = 0; r < 4; ++r) {
            float rg = sigmf(gi[0][r] + bir_ + gh[0][r] + bhr_);
            float zg = sigmf(gi[1][r] + biz_ + gh[1][r] + bhz_);
            float ng2 = tanhfast(gi[2][r] + bin_ + rg * (gh[2][r] + bhn_));
            float ho = ng2 + zg * (hp[r] - ng2);
            sA[quad * 4 + r][nr] = f2bfn(ho);
        }
    }

    // ---- capture h_out fragments, store h_out (sA dies; sV/sO overlay) ----
    bf16x8 af[4];
#pragma unroll
    for (int kt = 0; kt < 4; ++kt)
        af[kt] = ld8(&sA[l15][kt * 32 + quad * 8]);
    {
        float* out_h = out + (size_t)SIZE * 10;
#pragma unroll 1
        for (int it = 0; it < 8; ++it) {
            int idx = it * 256 + lane * 4;   // over [16][128]
            int rr = idx >> 7, cc = idx & 127;
            int grow = wrow0 + rr;
            if (grow < SIZE) {
                float2 p0 = make_float2(bf2f(sA[rr][cc]),     bf2f(sA[rr][cc + 1]));
                float2 p1 = make_float2(bf2f(sA[rr][cc + 2]), bf2f(sA[rr][cc + 3]));
                float* dst = out_h + (size_t)grow * 128 + cc;
                *reinterpret_cast<float2*>(dst)     = p0;
                *reinterpret_cast<float2*>(dst + 2) = p1;
            }
        }
    }

    // ---- Phase 3: V = relu(H_OUT @ v_w^T + v_b) -> sV (overlay), chunks 0..3 ----
#pragma unroll 1
    for (int nt = 0; nt < 4; ++nt) {
        const int cur = nt & 1;
        if (nt < 3) stage_seq(wbuf[cur ^ 1], wsw + WS_VW + (nt + 1) * 2048, 4, wave, lane);
        else        stage_seq(wbuf[cur ^ 1], wsw + WS_DECW, 6, wave, lane);  // phase-4 chunk
        const float bias = v_b[nt * 16 + l15];
        floatx4 a0 = floatx4{0.f,0.f,0.f,0.f};
#pragma unroll
        for (int kt = 0; kt < 4; ++kt) {
            bf16x8 b = ld8(&wbuf[cur][kt * 512 + lane * 8]);
            a0 = __builtin_amdgcn_mfma_f32_16x16x32_bf16(af[kt], b, a0, 0, 0, 0);
        }
#pragma unroll
        for (int r = 0; r < 4; ++r)
            sV[quad * 4 + r][nt * 16 + l15] = f2bfn(fmaxf(a0[r] + bias, 0.f));
        __syncthreads();
    }

    // ---- Phase 4: OUT = [H_OUT|V] @ dec_w^T + dec_b (weights in wbuf[0]) ----
    {
        floatx4 d0 = floatx4{0.f,0.f,0.f,0.f};
#pragma unroll
        for (int kt = 0; kt < 6; ++kt) {
            bf16x8 b = ld8(&wbuf[0][kt * 512 + lane * 8]);
            bf16x8 a0 = (kt < 4) ? af[kt] : ld8(&sV[l15][(kt - 4) * 32 + quad * 8]);
            d0 = __builtin_amdgcn_mfma_f32_16x16x32_bf16(a0, b, d0, 0, 0, 0);
        }
        if (l15 < 10) {
            const float bias = dec_b[l15];
#pragma unroll
            for (int r = 0; r < 4; ++r)
                sO[(quad * 4 + r) * 10 + l15] = d0[r] + bias;
        }
        // coalesced store: 160 consecutive f32 per wave
#pragma unroll
        for (int j = 0; j < 3; ++j) {
            int idx = j * 64 + lane;          // 0..191, use 0..159
            if (idx < 160) {
                int row = idx / 10, col = idx % 10;
                int grow = wrow0 + row;
                if (grow < SIZE)
                    out[(size_t)grow * 10 + col] = sO[row * 10 + col];
            }
        }
    }
}

extern "C" void kernel_launch(void* const* d_in, const int* in_sizes, int n_in,
                              void* d_out, int out_size, void* d_ws, size_t ws_size,
                              hipStream_t stream) {
    const float* obs   = (const float*)d_in[0];
    const float* hid   = (const float*)d_in[1];
    const float* enc_w = (const float*)d_in[2];
    const float* enc_b = (const float*)d_in[3];
    const float* w_ih  = (const float*)d_in[4];
    const float* w_hh  = (const float*)d_in[5];
    const float* b_ih  = (const float*)d_in[6];
    const float* b_hh  = (const float*)d_in[7];
    // d_in[8..19]: dead code (bi-GRU / hard attention / q,k) — unused.
    const float* v_w   = (const float*)d_in[20];
    const float* v_b   = (const float*)d_in[21];
    const float* dec_w = (const float*)d_in[22];
    const float* dec_b = (const float*)d_in[23];
    unsigned short* wsw = (unsigned short*)d_ws;
    float* out = (float*)d_out;

    hipLaunchKernelGGL(cvt_weights, dim3((WS_TOTC + 255) / 256), dim3(256), 0, stream,
                       enc_w, w_ih, w_hh, v_w, dec_w, wsw);
    // 512 blocks x 8 waves x 16 rows = 65536 >= 65535; LDS 50KB -> 3 blocks/CU
    hipLaunchKernelGGL(attn_critic_kernel, dim3(512), dim3(512), 0, stream,
                       obs, hid, enc_b, b_ih, b_hh, v_b, dec_b, wsw, out);
}